// Round 12
// baseline (32.437 us; speedup 1.0000x reference)
//
#include <hip/hip_runtime.h>
#include <math.h>

#define NB 64
#define NO 32
#define NP 5456
#define NC 80
#define NSLOT 45
#define EPSF 1e-7f
#define NFB 2728                 // focal blocks; 2728*256*10 float4 = total4 exactly
#define NBLK (NB + NFB)          // 2792 total blocks

// ---------- focal (shared subexpressions) ----------
// t=e^x, u=1+t, r=1/u, p=sigmoid(x)=t*r, sp=softplus(x)=log u
// neg = 0.75*p^2*sp (0.75 factored out); pos-neg in focal_corr.
__device__ __forceinline__ float pps(float x) {      // p*p*softplus(x)
    float t = __expf(x);
    float u = 1.f + t;
    float r = __builtin_amdgcn_rcpf(u);
    float p = t * r;
    float sp = __logf(u);
    return p * p * sp;
}
__device__ __forceinline__ float focal_corr(float x) {
    float t = __expf(x);
    float u = 1.f + t;
    float r = __builtin_amdgcn_rcpf(u);
    float p = t * r;
    float sp = __logf(u);
    return 0.25f * r * r * (sp - x) - 0.75f * p * p * sp;
}

__device__ __forceinline__ unsigned long long pkkey(float d, int j) {
    return ((unsigned long long)__float_as_uint(d) << 32) | (unsigned)j;
}

// ---------- analytic priors (bit-exact vs float64->float32 input) ----------
__device__ __forceinline__ float2 prior_center(int gp) {
    int lidx, shift; float invf;
    if (gp < 4096)      { lidx = gp;        shift = 6; invf = 1.f/64.f; }
    else if (gp < 5120) { lidx = gp - 4096; shift = 5; invf = 1.f/32.f; }
    else if (gp < 5376) { lidx = gp - 5120; shift = 4; invf = 1.f/16.f; }
    else if (gp < 5440) { lidx = gp - 5376; shift = 3; invf = 1.f/8.f;  }
    else                { lidx = gp - 5440; shift = 2; invf = 1.f/4.f;  }
    int iy = lidx >> shift, ix = lidx & ((1 << shift) - 1);
    return make_float2((ix + 0.5f) * invf, (iy + 0.5f) * invf);
}
__device__ __forceinline__ float prior_scale(int gp) {
    return gp < 4096 ? 0.07f : gp < 5120 ? 0.15f :
           gp < 5376 ? 0.3f  : gp < 5440 ? 0.45f : 0.6f;
}

// ---------- kernel A: assign (bid<NB) | focal (else) ----------
// Cross-block results are consumed ONLY by combine_kernel (kernel boundary =
// the coherence fence; same-kernel cross-XCD reads proved stale in R11).
__global__ __launch_bounds__(256, 8) void fused_all(
    const float4* __restrict__ sc4,      // [total4]
    const float4* __restrict__ locs,     // [NB*NP]
    const float4* __restrict__ boxes,    // [NB*NO]
    const int*    __restrict__ labels,   // [NB*NO]
    const float*  __restrict__ scores,   // [NB*NP*NC]
    float* __restrict__ partial,         // [NFB]
    float* __restrict__ corr,            // [NB]
    int*   __restrict__ npb,             // [NB]
    float* __restrict__ ciouS,           // [NB]
    int*   __restrict__ ciouC)           // [NB]
{
    const int bid = (int)blockIdx.x;

    if (bid >= NB) {
        // -------- focal: 5 phases x 2 float4, A/B ping-pong, high TLP --------
        const int fb  = bid - NB;                    // 0..NFB-1
        const int tid = (int)threadIdx.x;
        float4 A0, A1, B0, B1;
        float lsum = 0.f;

        #define ISSUE_A(ph) { const float4* p = sc4 + (((size_t)(ph)*NFB + fb)*2)*256 + tid; \
            A0 = p[0]; A1 = p[256]; }
        #define ISSUE_B(ph) { const float4* p = sc4 + (((size_t)(ph)*NFB + fb)*2)*256 + tid; \
            B0 = p[0]; B1 = p[256]; }
        #define COMP(v) lsum += pps(v.x) + pps(v.y) + pps(v.z) + pps(v.w);
        #define COMP_A { COMP(A0) COMP(A1) }
        #define COMP_B { COMP(B0) COMP(B1) }

        ISSUE_A(0);
        ISSUE_B(1); COMP_A;          // phase 0
        ISSUE_A(2); COMP_B;          // phase 1
        ISSUE_B(3); COMP_A;          // phase 2
        ISSUE_A(4); COMP_B;          // phase 3
        COMP_A;                      // phase 4

        #pragma unroll
        for (int off = 32; off > 0; off >>= 1) lsum += __shfl_down(lsum, off);
        __shared__ float wsum[4];
        const int lane = tid & 63, wid = tid >> 6;
        if (lane == 0) wsum[wid] = lsum;
        __syncthreads();
        if (tid == 0)
            partial[fb] = 0.75f * (wsum[0] + wsum[1] + wsum[2] + wsum[3]);
        return;
    }

    // ---------------- assign block: whole image b, zero prior loads ----------
    const int b    = bid;
    const int wv   = threadIdx.x >> 6;    // 0..3
    const int lane = threadIdx.x & 63;
    const int half = lane >> 5;           // 2 GTs per wave simultaneously
    const int hl   = lane & 31;
    const int t    = threadIdx.x;

    __shared__ unsigned long long s_key[2][4][64];   // parity double-buffer
    __shared__ int    s_ci[NO * NSLOT];
    __shared__ float  s_io[NO * NSLOT];
    __shared__ float  s_thr[NO];
    __shared__ int    s_pidx[NSLOT], s_ob[NSLOT], s_match[NSLOT];
    __shared__ float4 s_dec[NSLOT];

    const int   FM[5]   = {64, 32, 16, 8, 4};
    const int   OFS[5]  = {0, 4096, 5120, 5376, 5440};
    const float INVF[5] = {1.f/64.f, 1.f/32.f, 1.f/16.f, 1.f/8.f, 1.f/4.f};
    const float SC[5]   = {0.07f, 0.15f, 0.3f, 0.45f, 0.6f};

    // Phase A: windowed top-9 per (GT, level). 5x5 window: 9th-NN <= 2.121h,
    // everything outside +/-2 ring >= 2.5h -> exact top-9 + exact ranks.
    for (int q = 0; q < 4; ++q) {
        const int o = wv * 8 + q * 2 + half;
        const float4 a = boxes[b * NO + o];
        const float gx = (a.x + a.z) * 0.5f, gy = (a.y + a.w) * 0.5f;
        const float area_a = (a.z - a.x) * (a.w - a.y);

        #pragma unroll
        for (int l = 0; l < 5; ++l) {
            const int f = FM[l], base = OFS[l];
            const int win = (l < 4) ? 5 : 4, nc = win * win;
            const float invf = INVF[l], s = SC[l];

            int ix0 = 0, iy0 = 0;
            if (l < 4) {
                int ixn = (int)(gx * (float)f);       // >0: trunc == floor
                int iyn = (int)(gy * (float)f);
                ix0 = min(max(ixn - 2, 0), f - 5);
                iy0 = min(max(iyn - 2, 0), f - 5);
            }

            const bool act = hl < nc;
            const int wx = act ? (hl % win) : 0;
            const int wy = act ? (hl / win) : 0;
            const int ix = ix0 + wx, iy = iy0 + wy;
            const int lidx = iy * f + ix;

            unsigned long long mykey = ~0ull;
            float pcx = 0.f, pcy = 0.f;
            if (act) {
                pcx = (ix + 0.5f) * invf;             // bit-exact prior center
                pcy = (iy + 0.5f) * invf;
                float dx = gx - pcx, dy = gy - pcy;
                float d = __fsqrt_rn(__fadd_rn(__fmul_rn(dx, dx), __fmul_rn(dy, dy)));
                mykey = pkkey(d, lidx);
            }
            const int par = (q * 5 + l) & 1;
            s_key[par][wv][lane] = mykey;
            __syncthreads();

            int rank = 0;
            #pragma unroll
            for (int j = 0; j < nc; ++j)              // broadcast LDS reads
                rank += (s_key[par][wv][half * 32 + j] < mykey) ? 1 : 0;

            if (act && rank < 9) {
                float hs = s * 0.5f;
                float bx0 = pcx - hs, by0 = pcy - hs;
                float bx1 = pcx + hs, by1 = pcy + hs;
                float w = fmaxf(fminf(a.z, bx1) - fmaxf(a.x, bx0), 0.f);
                float h = fmaxf(fminf(a.w, by1) - fmaxf(a.y, by0), 0.f);
                float inter  = w * h;
                float area_b = (bx1 - bx0) * (by1 - by0);
                float iou = inter / (area_a + area_b - inter + EPSF);
                s_ci[o * NSLOT + l * 9 + rank] = base + lidx;
                s_io[o * NSLOT + l * 9 + rank] = iou;
            }
        }
    }
    __syncthreads();

    // Phase B1: per-GT threshold, sequential sum order (t<32), pure LDS
    if (t < NO) {
        float sum = 0.f;
        #pragma unroll
        for (int k = 0; k < NSLOT; ++k) sum += s_io[t * NSLOT + k];
        float mean = sum / 45.f;
        float var = 0.f;
        #pragma unroll
        for (int k = 0; k < NSLOT; ++k) { float d = s_io[t * NSLOT + k] - mean; var += d * d; }
        s_thr[t] = mean + sqrtf(var / 44.f);
    }
    __syncthreads();

    // Phase B2: masked iou, 256 threads (8 lanes per GT), analytic inside-test
    {
        const int o = t >> 3;
        const float thr = s_thr[o];
        const float4 a = boxes[b * NO + o];
        for (int k = (t & 7); k < NSLOT; k += 8) {
            int gp = s_ci[o * NSLOT + k];
            float2 pc = prior_center(gp);
            bool inside = (a.x < pc.x) && (pc.x < a.z) && (a.y < pc.y) && (pc.y < a.w);
            float pov = s_io[o * NSLOT + k];
            s_io[o * NSLOT + k] = (pov > thr && inside) ? pov : 0.f;
        }
    }
    __syncthreads();

    // Phase C: per-slot argmax over 32 GTs (4 lanes/slot, first-max ties) + decode
    if (t < NSLOT * 4) {
        const int slot = t >> 2, g = t & 3;
        float bv = -1.f; int ob = 32;
        #pragma unroll
        for (int i = 0; i < 8; ++i) {
            int oo = g * 8 + i;
            float v = s_io[oo * NSLOT + slot];
            if (v > bv) { bv = v; ob = oo; }      // strict >: first max in chunk
        }
        #pragma unroll
        for (int off = 1; off < 4; off <<= 1) {   // 4-lane groups, wave-aligned
            float ov = __shfl_xor(bv, off);
            int   oo = __shfl_xor(ob, off);
            if (ov > bv || (ov == bv && oo < ob)) { bv = ov; ob = oo; }
        }
        if (g == 0) {
            int match = bv > 0.f;
            int pidx = s_ci[ob * NSLOT + slot];
            s_pidx[slot] = pidx; s_ob[slot] = ob; s_match[slot] = match;
            float4 lc = locs[b * NP + pidx];
            float  sc = prior_scale(pidx);
            float2 pc = prior_center(pidx);
            float cx = lc.x * sc / 10.f + pc.x;
            float cy = lc.y * sc / 10.f + pc.y;
            float wd = expf(lc.z / 5.f) * sc;
            float hd = expf(lc.w / 5.f) * sc;
            s_dec[slot] = make_float4(cx - wd * 0.5f, cy - hd * 0.5f,
                                      cx + wd * 0.5f, cy + hd * 0.5f);
        }
    }
    __syncthreads();

    // Phase D/E: ciou + last-writer label corr + counts (wave 0)
    if (t < 64) {
        const int matched = (t < NSLOT) ? s_match[t] : 0;

        float cl = 0.f;
        if (matched) {
            float4 p = s_dec[t], t4 = boxes[b * NO + s_ob[t]];
            float pw = p.z - p.x, ph = p.w - p.y;
            float tw = t4.z - t4.x, th = t4.w - t4.y;
            float iw = fmaxf(fminf(p.z, t4.z) - fmaxf(p.x, t4.x), 0.f);
            float ih = fmaxf(fminf(p.w, t4.w) - fmaxf(p.y, t4.y), 0.f);
            float inter = iw * ih;
            float uni = pw * ph + tw * th - inter;
            float iou = inter / (uni + EPSF);
            float cw = fmaxf(p.z, t4.z) - fminf(p.x, t4.x);
            float ch = fmaxf(p.w, t4.w) - fminf(p.y, t4.y);
            float c2 = cw * cw + ch * ch + EPSF;
            float ddx = p.x + p.z - t4.x - t4.z, ddy = p.y + p.w - t4.y - t4.w;
            float rho2 = (ddx * ddx + ddy * ddy) * 0.25f;
            float dv = atanf(tw / (th + EPSF)) - atanf(pw / (ph + EPSF));
            float v = (float)(4.0 / (M_PI * M_PI)) * dv * dv;
            float al = v / (1.f - iou + v + EPSF);
            cl = 1.f - iou + rho2 / c2 + al * v;
        }

        float mycorr = 0.f; int firstocc = 0;
        if (matched) {
            bool last = true, first = true;
            #pragma unroll
            for (int s2 = 0; s2 < NSLOT; ++s2) {
                bool same = s_match[s2] && (s_pidx[s2] == s_pidx[t]);
                if (same && s2 > t) last = false;
                if (same && s2 < t) first = false;
            }
            if (last) {
                int lab = labels[b * NO + s_ob[t]];
                float x = scores[((size_t)b * NP + s_pidx[t]) * NC + (lab - 1)];
                mycorr = focal_corr(x);
            }
            firstocc = first;
        }

        unsigned long long ballm = __ballot(matched);
        unsigned long long ballf = __ballot(firstocc);
        #pragma unroll
        for (int off = 32; off > 0; off >>= 1) {
            cl     += __shfl_down(cl, off);
            mycorr += __shfl_down(mycorr, off);
        }
        if (t == 0) {
            corr[b]  = mycorr;
            npb[b]   = (int)__popcll(ballf);
            ciouS[b] = cl;
            ciouC[b] = (int)__popcll(ballm);
        }
    }
}

// ---------- kernel B: final combine (kernel boundary = coherence fence) -----
__global__ __launch_bounds__(256) void combine_kernel(
    const float* __restrict__ partial,   // [NFB]
    const float* __restrict__ corr,      // [NB]
    const int*   __restrict__ npb,       // [NB]
    const float* __restrict__ ciouS,     // [NB]
    const int*   __restrict__ ciouC,     // [NB]
    float* __restrict__ out)
{
    const int t = threadIdx.x;
    double fsum = 0.0;
    for (int i = t; i < NFB; i += 256) fsum += (double)partial[i];

    float crs = 0.f, cs = 0.f; int np = 0, cc = 0;
    if (t < NB) { crs = corr[t]; np = npb[t]; cs = ciouS[t]; cc = ciouC[t]; }

    #pragma unroll
    for (int off = 32; off > 0; off >>= 1) {
        fsum += __shfl_down(fsum, off);
        crs  += __shfl_down(crs, off);
        cs   += __shfl_down(cs, off);
        np   += __shfl_down(np, off);
        cc   += __shfl_down(cc, off);
    }
    __shared__ double sd[4];
    const int lane = t & 63, wid = t >> 6;
    if (lane == 0) sd[wid] = fsum;
    __syncthreads();
    if (t == 0) {
        double ftot = sd[0] + sd[1] + sd[2] + sd[3] + (double)crs;
        int npv = np < 1 ? 1 : np;
        int ccv = cc < 1 ? 1 : cc;
        out[0] = (float)(ftot / (double)npv + (double)cs / (double)ccv);
    }
}

extern "C" void kernel_launch(void* const* d_in, const int* in_sizes, int n_in,
                              void* d_out, int out_size, void* d_ws, size_t ws_size,
                              hipStream_t stream)
{
    const float* locs   = (const float*)d_in[0];
    const float* scores = (const float*)d_in[1];
    const float* boxes  = (const float*)d_in[2];
    const int*   labels = (const int*)d_in[3];

    char* ws = (char*)d_ws;
    float* partial = (float*)(ws + 0);                    // NFB floats = 10912 B
    float* corr    = (float*)(ws + 11008);
    int*   npb     = (int*)(ws + 11264);
    float* ciouS   = (float*)(ws + 11520);
    int*   ciouC   = (int*)(ws + 11776);

    // no memsets, no atomics: every scratch word is written unconditionally
    // each call. Deterministic across replays.

    fused_all<<<NBLK, 256, 0, stream>>>(
        (const float4*)scores, (const float4*)locs, (const float4*)boxes,
        labels, scores, partial, corr, npb, ciouS, ciouC);

    combine_kernel<<<1, 256, 0, stream>>>(partial, corr, npb, ciouS, ciouC, (float*)d_out);
}

// Round 14
// 30.863 us; speedup vs baseline: 1.0510x; 1.0510x over previous
//
#include <hip/hip_runtime.h>
#include <math.h>

#define NB 64
#define NO 32
#define NP 5456
#define NC 80
#define NSLOT 45
#define EPSF 1e-7f
#define NFB 2728                 // focal blocks; 2728*256*10 float4 = total4 exactly
#define NBLK (NB + NFB)          // 2792 total blocks

typedef float floatx4 __attribute__((ext_vector_type(4)));  // native vec for nt-load

// ---------- focal (shared subexpressions) ----------
// t=e^x, u=1+t, r=1/u, p=sigmoid(x)=t*r, sp=softplus(x)=log u
// neg = 0.75*p^2*sp (0.75 factored out); pos-neg in focal_corr.
__device__ __forceinline__ float pps(float x) {      // p*p*softplus(x)
    float t = __expf(x);
    float u = 1.f + t;
    float r = __builtin_amdgcn_rcpf(u);
    float p = t * r;
    float sp = __logf(u);
    return p * p * sp;
}
__device__ __forceinline__ float focal_corr(float x) {
    float t = __expf(x);
    float u = 1.f + t;
    float r = __builtin_amdgcn_rcpf(u);
    float p = t * r;
    float sp = __logf(u);
    return 0.25f * r * r * (sp - x) - 0.75f * p * p * sp;
}

__device__ __forceinline__ unsigned long long pkkey(float d, int j) {
    return ((unsigned long long)__float_as_uint(d) << 32) | (unsigned)j;
}

// ---------- analytic priors (bit-exact vs float64->float32 input) ----------
__device__ __forceinline__ float2 prior_center(int gp) {
    int lidx, shift; float invf;
    if (gp < 4096)      { lidx = gp;        shift = 6; invf = 1.f/64.f; }
    else if (gp < 5120) { lidx = gp - 4096; shift = 5; invf = 1.f/32.f; }
    else if (gp < 5376) { lidx = gp - 5120; shift = 4; invf = 1.f/16.f; }
    else if (gp < 5440) { lidx = gp - 5376; shift = 3; invf = 1.f/8.f;  }
    else                { lidx = gp - 5440; shift = 2; invf = 1.f/4.f;  }
    int iy = lidx >> shift, ix = lidx & ((1 << shift) - 1);
    return make_float2((ix + 0.5f) * invf, (iy + 0.5f) * invf);
}
__device__ __forceinline__ float prior_scale(int gp) {
    return gp < 4096 ? 0.07f : gp < 5120 ? 0.15f :
           gp < 5376 ? 0.3f  : gp < 5440 ? 0.45f : 0.6f;
}

// ---------- kernel A: assign (bid<NB) | focal (else) ----------
// Cross-block results are consumed ONLY by combine_kernel (kernel boundary =
// the coherence fence; same-kernel cross-XCD reads proved stale in R11).
__global__ __launch_bounds__(256, 8) void fused_all(
    const floatx4* __restrict__ sc4,     // [total4]
    const float4* __restrict__ locs,     // [NB*NP]
    const float4* __restrict__ boxes,    // [NB*NO]
    const int*    __restrict__ labels,   // [NB*NO]
    const float*  __restrict__ scores,   // [NB*NP*NC]
    float* __restrict__ partial,         // [NFB]
    float* __restrict__ corr,            // [NB]
    int*   __restrict__ npb,             // [NB]
    float* __restrict__ ciouS,           // [NB]
    int*   __restrict__ ciouC)           // [NB]
{
    const int bid = (int)blockIdx.x;

    if (bid >= NB) {
        // ---- focal: 5 phases x 2 float4, ping-pong, NON-TEMPORAL stream ----
        // nt loads bypass L2/L3 -> pure HBM stream (6.3 TB/s achievable) and
        // no L3 thrash; scores has zero reuse inside a dispatch.
        const int fb  = bid - NB;                    // 0..NFB-1
        const int tid = (int)threadIdx.x;
        floatx4 A0, A1, B0, B1;
        float lsum = 0.f;

        #define ISSUE_A(ph) { const floatx4* p = sc4 + (((size_t)(ph)*NFB + fb)*2)*256 + tid; \
            A0 = __builtin_nontemporal_load(p); A1 = __builtin_nontemporal_load(p + 256); }
        #define ISSUE_B(ph) { const floatx4* p = sc4 + (((size_t)(ph)*NFB + fb)*2)*256 + tid; \
            B0 = __builtin_nontemporal_load(p); B1 = __builtin_nontemporal_load(p + 256); }
        #define COMP(v) lsum += pps(v.x) + pps(v.y) + pps(v.z) + pps(v.w);
        #define COMP_A { COMP(A0) COMP(A1) }
        #define COMP_B { COMP(B0) COMP(B1) }

        ISSUE_A(0);
        ISSUE_B(1); COMP_A;          // phase 0
        ISSUE_A(2); COMP_B;          // phase 1
        ISSUE_B(3); COMP_A;          // phase 2
        ISSUE_A(4); COMP_B;          // phase 3
        COMP_A;                      // phase 4

        #pragma unroll
        for (int off = 32; off > 0; off >>= 1) lsum += __shfl_down(lsum, off);
        __shared__ float wsum[4];
        const int lane = tid & 63, wid = tid >> 6;
        if (lane == 0) wsum[wid] = lsum;
        __syncthreads();
        if (tid == 0)
            partial[fb] = 0.75f * (wsum[0] + wsum[1] + wsum[2] + wsum[3]);
        return;
    }

    // ---------------- assign block: whole image b, zero prior loads ----------
    const int b    = bid;
    const int wv   = threadIdx.x >> 6;    // 0..3
    const int lane = threadIdx.x & 63;
    const int half = lane >> 5;           // 2 GTs per wave simultaneously
    const int hl   = lane & 31;
    const int t    = threadIdx.x;

    __shared__ unsigned long long s_key[2][4][64];   // parity double-buffer
    __shared__ int    s_ci[NO * NSLOT];
    __shared__ float  s_io[NO * NSLOT];
    __shared__ float  s_thr[NO];
    __shared__ int    s_pidx[NSLOT], s_ob[NSLOT], s_match[NSLOT];
    __shared__ float4 s_dec[NSLOT];

    const int   FM[5]   = {64, 32, 16, 8, 4};
    const int   OFS[5]  = {0, 4096, 5120, 5376, 5440};
    const float INVF[5] = {1.f/64.f, 1.f/32.f, 1.f/16.f, 1.f/8.f, 1.f/4.f};
    const float SC[5]   = {0.07f, 0.15f, 0.3f, 0.45f, 0.6f};

    // Phase A: windowed top-9 per (GT, level). 5x5 window: 9th-NN <= 2.121h,
    // everything outside +/-2 ring >= 2.5h -> exact top-9 + exact ranks.
    for (int q = 0; q < 4; ++q) {
        const int o = wv * 8 + q * 2 + half;
        const float4 a = boxes[b * NO + o];
        const float gx = (a.x + a.z) * 0.5f, gy = (a.y + a.w) * 0.5f;
        const float area_a = (a.z - a.x) * (a.w - a.y);

        #pragma unroll
        for (int l = 0; l < 5; ++l) {
            const int f = FM[l], base = OFS[l];
            const int win = (l < 4) ? 5 : 4, nc = win * win;
            const float invf = INVF[l], s = SC[l];

            int ix0 = 0, iy0 = 0;
            if (l < 4) {
                int ixn = (int)(gx * (float)f);       // >0: trunc == floor
                int iyn = (int)(gy * (float)f);
                ix0 = min(max(ixn - 2, 0), f - 5);
                iy0 = min(max(iyn - 2, 0), f - 5);
            }

            const bool act = hl < nc;
            const int wx = act ? (hl % win) : 0;
            const int wy = act ? (hl / win) : 0;
            const int ix = ix0 + wx, iy = iy0 + wy;
            const int lidx = iy * f + ix;

            unsigned long long mykey = ~0ull;
            float pcx = 0.f, pcy = 0.f;
            if (act) {
                pcx = (ix + 0.5f) * invf;             // bit-exact prior center
                pcy = (iy + 0.5f) * invf;
                float dx = gx - pcx, dy = gy - pcy;
                float d = __fsqrt_rn(__fadd_rn(__fmul_rn(dx, dx), __fmul_rn(dy, dy)));
                mykey = pkkey(d, lidx);
            }
            const int par = (q * 5 + l) & 1;
            s_key[par][wv][lane] = mykey;
            __syncthreads();

            int rank = 0;
            #pragma unroll
            for (int j = 0; j < nc; ++j)              // broadcast LDS reads
                rank += (s_key[par][wv][half * 32 + j] < mykey) ? 1 : 0;

            if (act && rank < 9) {
                float hs = s * 0.5f;
                float bx0 = pcx - hs, by0 = pcy - hs;
                float bx1 = pcx + hs, by1 = pcy + hs;
                float w = fmaxf(fminf(a.z, bx1) - fmaxf(a.x, bx0), 0.f);
                float h = fmaxf(fminf(a.w, by1) - fmaxf(a.y, by0), 0.f);
                float inter  = w * h;
                float area_b = (bx1 - bx0) * (by1 - by0);
                float iou = inter / (area_a + area_b - inter + EPSF);
                s_ci[o * NSLOT + l * 9 + rank] = base + lidx;
                s_io[o * NSLOT + l * 9 + rank] = iou;
            }
        }
    }
    __syncthreads();

    // Phase B1: per-GT threshold, sequential sum order (t<32), pure LDS
    if (t < NO) {
        float sum = 0.f;
        #pragma unroll
        for (int k = 0; k < NSLOT; ++k) sum += s_io[t * NSLOT + k];
        float mean = sum / 45.f;
        float var = 0.f;
        #pragma unroll
        for (int k = 0; k < NSLOT; ++k) { float d = s_io[t * NSLOT + k] - mean; var += d * d; }
        s_thr[t] = mean + sqrtf(var / 44.f);
    }
    __syncthreads();

    // Phase B2: masked iou, 256 threads (8 lanes per GT), analytic inside-test
    {
        const int o = t >> 3;
        const float thr = s_thr[o];
        const float4 a = boxes[b * NO + o];
        for (int k = (t & 7); k < NSLOT; k += 8) {
            int gp = s_ci[o * NSLOT + k];
            float2 pc = prior_center(gp);
            bool inside = (a.x < pc.x) && (pc.x < a.z) && (a.y < pc.y) && (pc.y < a.w);
            float pov = s_io[o * NSLOT + k];
            s_io[o * NSLOT + k] = (pov > thr && inside) ? pov : 0.f;
        }
    }
    __syncthreads();

    // Phase C: per-slot argmax over 32 GTs (4 lanes/slot, first-max ties) + decode
    if (t < NSLOT * 4) {
        const int slot = t >> 2, g = t & 3;
        float bv = -1.f; int ob = 32;
        #pragma unroll
        for (int i = 0; i < 8; ++i) {
            int oo = g * 8 + i;
            float v = s_io[oo * NSLOT + slot];
            if (v > bv) { bv = v; ob = oo; }      // strict >: first max in chunk
        }
        #pragma unroll
        for (int off = 1; off < 4; off <<= 1) {   // 4-lane groups, wave-aligned
            float ov = __shfl_xor(bv, off);
            int   oo = __shfl_xor(ob, off);
            if (ov > bv || (ov == bv && oo < ob)) { bv = ov; ob = oo; }
        }
        if (g == 0) {
            int match = bv > 0.f;
            int pidx = s_ci[ob * NSLOT + slot];
            s_pidx[slot] = pidx; s_ob[slot] = ob; s_match[slot] = match;
            float4 lc = locs[b * NP + pidx];
            float  sc = prior_scale(pidx);
            float2 pc = prior_center(pidx);
            float cx = lc.x * sc / 10.f + pc.x;
            float cy = lc.y * sc / 10.f + pc.y;
            float wd = expf(lc.z / 5.f) * sc;
            float hd = expf(lc.w / 5.f) * sc;
            s_dec[slot] = make_float4(cx - wd * 0.5f, cy - hd * 0.5f,
                                      cx + wd * 0.5f, cy + hd * 0.5f);
        }
    }
    __syncthreads();

    // Phase D/E: ciou + last-writer label corr + counts (wave 0)
    if (t < 64) {
        const int matched = (t < NSLOT) ? s_match[t] : 0;

        float cl = 0.f;
        if (matched) {
            float4 p = s_dec[t], t4 = boxes[b * NO + s_ob[t]];
            float pw = p.z - p.x, ph = p.w - p.y;
            float tw = t4.z - t4.x, th = t4.w - t4.y;
            float iw = fmaxf(fminf(p.z, t4.z) - fmaxf(p.x, t4.x), 0.f);
            float ih = fmaxf(fminf(p.w, t4.w) - fmaxf(p.y, t4.y), 0.f);
            float inter = iw * ih;
            float uni = pw * ph + tw * th - inter;
            float iou = inter / (uni + EPSF);
            float cw = fmaxf(p.z, t4.z) - fminf(p.x, t4.x);
            float ch = fmaxf(p.w, t4.w) - fminf(p.y, t4.y);
            float c2 = cw * cw + ch * ch + EPSF;
            float ddx = p.x + p.z - t4.x - t4.z, ddy = p.y + p.w - t4.y - t4.w;
            float rho2 = (ddx * ddx + ddy * ddy) * 0.25f;
            float dv = atanf(tw / (th + EPSF)) - atanf(pw / (ph + EPSF));
            float v = (float)(4.0 / (M_PI * M_PI)) * dv * dv;
            float al = v / (1.f - iou + v + EPSF);
            cl = 1.f - iou + rho2 / c2 + al * v;
        }

        float mycorr = 0.f; int firstocc = 0;
        if (matched) {
            bool last = true, first = true;
            #pragma unroll
            for (int s2 = 0; s2 < NSLOT; ++s2) {
                bool same = s_match[s2] && (s_pidx[s2] == s_pidx[t]);
                if (same && s2 > t) last = false;
                if (same && s2 < t) first = false;
            }
            if (last) {
                int lab = labels[b * NO + s_ob[t]];
                float x = scores[((size_t)b * NP + s_pidx[t]) * NC + (lab - 1)];
                mycorr = focal_corr(x);
            }
            firstocc = first;
        }

        unsigned long long ballm = __ballot(matched);
        unsigned long long ballf = __ballot(firstocc);
        #pragma unroll
        for (int off = 32; off > 0; off >>= 1) {
            cl     += __shfl_down(cl, off);
            mycorr += __shfl_down(mycorr, off);
        }
        if (t == 0) {
            corr[b]  = mycorr;
            npb[b]   = (int)__popcll(ballf);
            ciouS[b] = cl;
            ciouC[b] = (int)__popcll(ballm);
        }
    }
}

// ---------- kernel B: final combine (kernel boundary = coherence fence) -----
__global__ __launch_bounds__(256) void combine_kernel(
    const float* __restrict__ partial,   // [NFB]
    const float* __restrict__ corr,      // [NB]
    const int*   __restrict__ npb,       // [NB]
    const float* __restrict__ ciouS,     // [NB]
    const int*   __restrict__ ciouC,     // [NB]
    float* __restrict__ out)
{
    const int t = threadIdx.x;
    double fsum = 0.0;
    for (int i = t; i < NFB; i += 256) fsum += (double)partial[i];

    float crs = 0.f, cs = 0.f; int np = 0, cc = 0;
    if (t < NB) { crs = corr[t]; np = npb[t]; cs = ciouS[t]; cc = ciouC[t]; }

    #pragma unroll
    for (int off = 32; off > 0; off >>= 1) {
        fsum += __shfl_down(fsum, off);
        crs  += __shfl_down(crs, off);
        cs   += __shfl_down(cs, off);
        np   += __shfl_down(np, off);
        cc   += __shfl_down(cc, off);
    }
    __shared__ double sd[4];
    const int lane = t & 63, wid = t >> 6;
    if (lane == 0) sd[wid] = fsum;
    __syncthreads();
    if (t == 0) {
        double ftot = sd[0] + sd[1] + sd[2] + sd[3] + (double)crs;
        int npv = np < 1 ? 1 : np;
        int ccv = cc < 1 ? 1 : cc;
        out[0] = (float)(ftot / (double)npv + (double)cs / (double)ccv);
    }
}

extern "C" void kernel_launch(void* const* d_in, const int* in_sizes, int n_in,
                              void* d_out, int out_size, void* d_ws, size_t ws_size,
                              hipStream_t stream)
{
    const float* locs   = (const float*)d_in[0];
    const float* scores = (const float*)d_in[1];
    const float* boxes  = (const float*)d_in[2];
    const int*   labels = (const int*)d_in[3];

    char* ws = (char*)d_ws;
    float* partial = (float*)(ws + 0);                    // NFB floats = 10912 B
    float* corr    = (float*)(ws + 11008);
    int*   npb     = (int*)(ws + 11264);
    float* ciouS   = (float*)(ws + 11520);
    int*   ciouC   = (int*)(ws + 11776);

    // no memsets, no atomics: every scratch word is written unconditionally
    // each call. Deterministic across replays.

    fused_all<<<NBLK, 256, 0, stream>>>(
        (const floatx4*)scores, (const float4*)locs, (const float4*)boxes,
        labels, scores, partial, corr, npb, ciouS, ciouC);

    combine_kernel<<<1, 256, 0, stream>>>(partial, corr, npb, ciouS, ciouC, (float*)d_out);
}